// Round 4
// baseline (779.277 us; speedup 1.0000x reference)
//
#include <hip/hip_runtime.h>

// Problem constants: B=32, IN=16, C=8192, U=32, K=16, 3 routing iters.
#define CC   8192
#define UU   32
#define KK   16
#define BB   32
#define INU  16
#define UK   512      // U*K
#define CPB  32       // channels per c-group
#define NBLK 512      // (CC/CPB) c-groups x 2 u-halves

typedef __attribute__((ext_vector_type(4))) float  f32x4;
typedef __attribute__((ext_vector_type(4))) __bf16 bf16x4;
typedef __attribute__((ext_vector_type(8))) __bf16 bf16x8;

// -------------------------------------------------------------------------
// One-time x transpose: xT[c][b*16+i] = x[b][i][c]  (proven).
// -------------------------------------------------------------------------
__global__ __launch_bounds__(256) void transpose_x(
    const float* __restrict__ x, float* __restrict__ xT)
{
    __shared__ float tile[64][65];
    const int bc = blockIdx.x & 127;           // 128 c-tiles of 64
    const int bb = blockIdx.x >> 7;            // 8 bi-tiles of 64 (B*IN = 512)
    const int c0 = bc * 64, bi0 = bb * 64;
    const int tx = threadIdx.x & 63, ty = threadIdx.x >> 6;  // 64 x 4
#pragma unroll
    for (int j = 0; j < 64; j += 4)
        tile[ty + j][tx] = x[(size_t)(bi0 + ty + j) * CC + (c0 + tx)];  // coalesced in c
    __syncthreads();
#pragma unroll
    for (int j = 0; j < 64; j += 4)                                      // coalesced in bi
        xT[(size_t)(c0 + ty + j) * (BB * INU) + (bi0 + tx)] = tile[tx][ty + j];
}

// -------------------------------------------------------------------------
// bf16 hi/lo split helpers — NO arrays, constant indices only (rule #20:
// any runtime-indexed ext_vector aggregate goes to scratch; round 3's 52-VGPR
// + 49MB spill-write signature came from exactly that).
// -------------------------------------------------------------------------
__device__ inline bf16x4 hi4(f32x4 f)
{
    bf16x4 h;
    h[0] = (__bf16)f[0]; h[1] = (__bf16)f[1];
    h[2] = (__bf16)f[2]; h[3] = (__bf16)f[3];
    return h;
}
__device__ inline bf16x4 lo4(f32x4 f, bf16x4 h)
{
    bf16x4 l;
    l[0] = (__bf16)(f[0] - (float)h[0]); l[1] = (__bf16)(f[1] - (float)h[1]);
    l[2] = (__bf16)(f[2] - (float)h[2]); l[3] = (__bf16)(f[3] - (float)h[3]);
    return l;
}
#define CAT8(a, b) __builtin_shufflevector((a), (b), 0, 1, 2, 3, 4, 5, 6, 7)

// -------------------------------------------------------------------------
// MFMA routing pass, u-split: block = (c-group, u-half); wave owns 2 u.
// Per channel c, per u: u_hat[16k x 32b] = W_cu[16,16] . x_c[16,32] via
// bf16x3-split MFMA: A=[wh|wl]; B1=[xh;xh] -> wh.xh+wl.xh; B2=[xl;0] -> wh.xl.
// Then a = (1/B) sum u_hat*v ; bnew = bio + a ; e = exp ; Z += e ; Sl += e*u_hat.
// Zero LDS, zero arrays -> all state in registers (~122 VGPR, 2 blk/CU).
// Fragment maps (verified by rounds 2-3 passing): A row=lane&15 (caps-k),
// contraction i=(lane>>4)*4+(j&3), half=j>>2; B col=lane&15 (b), same i map;
// D col=lane&15 (b), row=(lane>>4)*4+reg (caps-k).
// -------------------------------------------------------------------------
__global__ __launch_bounds__(512, 4) void fused_mfma(
    const float* __restrict__ W, const float* __restrict__ xT,
    const float* __restrict__ v_in, float* __restrict__ b_io,
    float* __restrict__ S, float* __restrict__ Z)
{
    const int tid  = threadIdx.x;
    const int w    = tid >> 6;                 // wave 0..7
    const int lane = tid & 63;
    const int col  = lane & 15;                // b within b-tile / caps-k row of A
    const int g    = lane >> 4;                // i-quad selector
    const int c0   = (blockIdx.x >> 1) * CPB;  // c-group
    const int u0   = (blockIdx.x & 1) * 16 + w * 2;  // this wave's 2 u's
    const int loff = col * 16 + g * 4;         // lane offset (floats) in a 1KB tile

    // v fragments: r is contiguous in memory -> plain vector loads.
    // Naming: {A,B} = u0+0 / u0+1 ; {0,1} = b-tile (b = col / 16+col).
    const float* vbase = v_in + (size_t)col * UK + u0 * KK + g * 4;
    f32x4 vfA0 = *(const f32x4*)(vbase);
    f32x4 vfB0 = *(const f32x4*)(vbase + KK);
    f32x4 vfA1 = *(const f32x4*)(vbase + 16 * UK);
    f32x4 vfB1 = *(const f32x4*)(vbase + 16 * UK + KK);

    f32x4 sA0 = {0.f, 0.f, 0.f, 0.f}, sA1 = sA0, sB0 = sA0, sB1 = sA0;
    float zl0 = 0.f, zl1 = 0.f;

    // Prime c = c0.
    f32x4 wf0, wf1, xf0, xf1;
    {
        const float* wb = W + ((size_t)c0 * UU + u0) * (KK * INU) + loff;
        wf0 = *(const f32x4*)(wb);
        wf1 = *(const f32x4*)(wb + 256);
        const float* xb = xT + (size_t)c0 * (BB * INU) + loff;
        xf0 = *(const f32x4*)(xb);
        xf1 = *(const f32x4*)(xb + 256);
    }

    const bf16x4 zb4 = {(__bf16)0.f, (__bf16)0.f, (__bf16)0.f, (__bf16)0.f};
    const f32x4  fz4 = {0.f, 0.f, 0.f, 0.f};

    for (int cc = 0; cc < CPB; ++cc) {
        const int c = c0 + cc;
        const bool have_next = (cc + 1 < CPB);

        // b_io: 8B L2 broadcast; consumed only after the MFMA+reduce chain.
        float2 bv = *(const float2*)(b_io + (size_t)c * UU + u0);

        // Prefetch c+1 (W = the HBM stream; x rides along).
        f32x4 wn0, wn1, xn0, xn1;
        if (have_next) {
            const float* wb = W + ((size_t)(c + 1) * UU + u0) * (KK * INU) + loff;
            wn0 = *(const f32x4*)(wb);
            wn1 = *(const f32x4*)(wb + 256);
            const float* xb = xT + (size_t)(c + 1) * (BB * INU) + loff;
            xn0 = *(const f32x4*)(xb);
            xn1 = *(const f32x4*)(xb + 256);
        }

        // x -> B operands (shared by both u-tiles).
        bf16x4 xh0 = hi4(xf0), xl0 = lo4(xf0, xh0);
        bf16x4 xh1 = hi4(xf1), xl1 = lo4(xf1, xh1);
        bf16x8 B1a = CAT8(xh0, xh0);   // [xhi ; xhi]
        bf16x8 B2a = CAT8(xl0, zb4);   // [xlo ;  0 ]
        bf16x8 B1b = CAT8(xh1, xh1);
        bf16x8 B2b = CAT8(xl1, zb4);

        // W -> A operands.
        bf16x4 wh0 = hi4(wf0), wl0 = lo4(wf0, wh0);
        bf16x4 wh1 = hi4(wf1), wl1 = lo4(wf1, wh1);
        bf16x8 Aa = CAT8(wh0, wl0);    // [Whi | Wlo]
        bf16x8 Ab = CAT8(wh1, wl1);

        // MFMAs: u_hat accumulators, named (no arrays).
        f32x4 aA0 = __builtin_amdgcn_mfma_f32_16x16x32_bf16(Aa, B1a, fz4, 0, 0, 0);
        aA0       = __builtin_amdgcn_mfma_f32_16x16x32_bf16(Aa, B2a, aA0, 0, 0, 0);
        f32x4 aA1 = __builtin_amdgcn_mfma_f32_16x16x32_bf16(Aa, B1b, fz4, 0, 0, 0);
        aA1       = __builtin_amdgcn_mfma_f32_16x16x32_bf16(Aa, B2b, aA1, 0, 0, 0);
        f32x4 aB0 = __builtin_amdgcn_mfma_f32_16x16x32_bf16(Ab, B1a, fz4, 0, 0, 0);
        aB0       = __builtin_amdgcn_mfma_f32_16x16x32_bf16(Ab, B2a, aB0, 0, 0, 0);
        f32x4 aB1 = __builtin_amdgcn_mfma_f32_16x16x32_bf16(Ab, B1b, fz4, 0, 0, 0);
        aB1       = __builtin_amdgcn_mfma_f32_16x16x32_bf16(Ab, B2b, aB1, 0, 0, 0);

        // Agreement: per-lane dot (vector FMA, constant extracts), wave reduce.
        f32x4 d0 = aA0 * vfA0 + aA1 * vfA1;
        f32x4 d1 = aB0 * vfB0 + aB1 * vfB1;
        float p0 = (d0[0] + d0[1]) + (d0[2] + d0[3]);
        float p1 = (d1[0] + d1[1]) + (d1[2] + d1[3]);
#pragma unroll
        for (int off = 1; off < 64; off <<= 1) {
            p0 += __shfl_xor(p0, off);
            p1 += __shfl_xor(p1, off);
        }

        // Routing update (identical on all lanes post-reduce).
        const float bn0 = bv.x + p0 * (1.0f / (float)BB);
        const float bn1 = bv.y + p1 * (1.0f / (float)BB);
        const float e0 = __expf(bn0);
        const float e1 = __expf(bn1);
        zl0 += e0; zl1 += e1;
        if (lane == 0) *(float2*)(b_io + (size_t)c * UU + u0) = make_float2(bn0, bn1);

        // S accumulation: vector FMA with scalar broadcast, register-resident.
        sA0 += aA0 * e0;  sA1 += aA1 * e0;
        sB0 += aB0 * e1;  sB1 += aB1 * e1;

        if (have_next) { wf0 = wn0; wf1 = wn1; xf0 = xn0; xf1 = xn1; }
    }

    // Flush S (hand-unrolled, constant extracts) and Z.
    {
        float* sb0 = S + (size_t)col * UK + u0 * KK + g * 4;          // bt=0 (b=col)
        float* sb1 = sb0 + 16 * UK;                                    // bt=1 (b=16+col)
        atomicAdd(sb0 + 0,      sA0[0]); atomicAdd(sb0 + 1,      sA0[1]);
        atomicAdd(sb0 + 2,      sA0[2]); atomicAdd(sb0 + 3,      sA0[3]);
        atomicAdd(sb0 + KK + 0, sB0[0]); atomicAdd(sb0 + KK + 1, sB0[1]);
        atomicAdd(sb0 + KK + 2, sB0[2]); atomicAdd(sb0 + KK + 3, sB0[3]);
        atomicAdd(sb1 + 0,      sA1[0]); atomicAdd(sb1 + 1,      sA1[1]);
        atomicAdd(sb1 + 2,      sA1[2]); atomicAdd(sb1 + 3,      sA1[3]);
        atomicAdd(sb1 + KK + 0, sB1[0]); atomicAdd(sb1 + KK + 1, sB1[1]);
        atomicAdd(sb1 + KK + 2, sB1[2]); atomicAdd(sb1 + KK + 3, sB1[3]);
    }
    if (lane == 0) {
        atomicAdd(Z + u0,     zl0);
        atomicAdd(Z + u0 + 1, zl1);
    }
}

// -------------------------------------------------------------------------
// Fallback pass (proven 175us LDS-broadcast kernel) — only if ws too small.
// -------------------------------------------------------------------------
__global__ __launch_bounds__(512, 2) void fused_pass_lds(
    const float* __restrict__ x, const float* __restrict__ W,
    const float* __restrict__ v_in, float* __restrict__ b_io,
    float* __restrict__ S, float* __restrict__ Z)
{
    __shared__ float xs[16 * 516];

    const int t   = threadIdx.x;
    const int bid = blockIdx.x;
    const int c0  = bid * 32;
    const int u   = t >> 4;
    const int k   = t & 15;

    float v[BB], Sl[BB], uh[BB];
#pragma unroll
    for (int b = 0; b < BB; ++b) { v[b] = v_in[b * UK + t]; Sl[b] = 0.f; }
    float zloc = 0.f;

    float4 w0, w1, w2, w3;
    {
        const float4* p = (const float4*)(W + ((size_t)c0 * UK + t) * INU);
        w0 = p[0]; w1 = p[1]; w2 = p[2]; w3 = p[3];
    }

    for (int cc = 0; cc < 32; ++cc) {
        if ((cc & 15) == 0) {
            __syncthreads();
            const int cbase = c0 + (cc & ~15);
            for (int j = 0; j < 16; ++j) {
                int idx = j * 512 + t;
                int ccl = idx & 15;
                int bi  = idx >> 4;
                xs[ccl * 516 + bi] = x[bi * CC + cbase + ccl];
            }
            __syncthreads();
        }

        float4 n0, n1, n2, n3;
        const bool have_next = (cc + 1 < 32);
        if (have_next) {
            const float4* p = (const float4*)(W + ((size_t)(c0 + cc + 1) * UK + t) * INU);
            n0 = p[0]; n1 = p[1]; n2 = p[2]; n3 = p[3];
        }

        const float* xrow = &xs[(cc & 15) * 516];
        float ap = 0.f;
#pragma unroll
        for (int b = 0; b < BB; ++b) {
            const float4* xr = (const float4*)(xrow + b * INU);
            float4 x0 = xr[0], x1 = xr[1], x2 = xr[2], x3 = xr[3];
            float h;
            h = w0.x * x0.x;
            h = fmaf(w0.y, x0.y, h); h = fmaf(w0.z, x0.z, h); h = fmaf(w0.w, x0.w, h);
            h = fmaf(w1.x, x1.x, h); h = fmaf(w1.y, x1.y, h);
            h = fmaf(w1.z, x1.z, h); h = fmaf(w1.w, x1.w, h);
            h = fmaf(w2.x, x2.x, h); h = fmaf(w2.y, x2.y, h);
            h = fmaf(w2.z, x2.z, h); h = fmaf(w2.w, x2.w, h);
            h = fmaf(w3.x, x3.x, h); h = fmaf(w3.y, x3.y, h);
            h = fmaf(w3.z, x3.z, h); h = fmaf(w3.w, x3.w, h);
            uh[b] = h;
            ap = fmaf(h, v[b], ap);
        }

        ap += __shfl_xor(ap, 8);
        ap += __shfl_xor(ap, 4);
        ap += __shfl_xor(ap, 2);
        ap += __shfl_xor(ap, 1);

        const int c = c0 + cc;
        float bnew = b_io[c * UU + u] + ap * (1.0f / (float)BB);
        float e = __expf(bnew);
        zloc += e;
        if (k == 0) b_io[c * UU + u] = bnew;

#pragma unroll
        for (int b = 0; b < BB; ++b) Sl[b] = fmaf(e, uh[b], Sl[b]);

        if (have_next) { w0 = n0; w1 = n1; w2 = n2; w3 = n3; }
    }

#pragma unroll
    for (int b = 0; b < BB; ++b) atomicAdd(S + b * UK + t, Sl[b]);
    if (k == 0) atomicAdd(Z + u, zloc);
}

// Normalize + squash: s = S/Z ; mag_sq[b,k] = sum_u s^2 ; v = msq/(1+msq)*s/mag.
__global__ void squash_k(const float* __restrict__ S, const float* __restrict__ Z,
                         float* __restrict__ vout)
{
    __shared__ float z_sh[UU];
    __shared__ float s2_sh[UK];
    __shared__ float mag_sh[KK];

    const int b = blockIdx.x;   // 32 blocks
    const int t = threadIdx.x;  // 512 = uk

    if (t < UU) z_sh[t] = Z[t];
    float ssum = S[b * UK + t];
    __syncthreads();

    float s = ssum / z_sh[t >> 4];
    s2_sh[t] = s * s;
    __syncthreads();

    if (t < KK) {
        float m = 0.f;
        for (int uu = 0; uu < UU; ++uu) m += s2_sh[uu * KK + t];
        mag_sh[t] = m;
    }
    __syncthreads();

    float msq = mag_sh[t & 15];
    float out = (msq / (1.0f + msq)) * s / sqrtf(msq);
    vout[b * UK + t] = out;
}

extern "C" void kernel_launch(void* const* d_in, const int* in_sizes, int n_in,
                              void* d_out, int out_size, void* d_ws, size_t ws_size,
                              hipStream_t stream)
{
    const float* x = (const float*)d_in[0];   // (B, IN, C)
    const float* W = (const float*)d_in[1];   // (C, U, K, IN)
    float* out = (float*)d_out;               // (B, U, K, 1) fp32

    char* ws = (char*)d_ws;

    // Workspace layout. Zero-init region is contiguous [0, 0x140200):
    //   [0x000000, 0x030000)  S3  : 3 x 64KB  (per-pass S -> no per-pass memset)
    //   [0x030000, 0x030180)  Z3  : 3 x 128B
    //   [0x030200, 0x040200)  vb  : 64KB
    //   [0x040200, 0x140200)  bio : 1MB
    //   [0x140400, ...     )  xT  : 16MB (fully written by transpose_x)
    const size_t XT_OFF = 0x140400;
    const size_t NEED   = XT_OFF + (size_t)CC * BB * INU * 4;

    if (ws_size >= NEED) {
        float* S3  = (float*)(ws);
        float* Z3  = (float*)(ws + 0x30000);
        float* vb  = (float*)(ws + 0x30200);
        float* bio = (float*)(ws + 0x40200);
        float* xT  = (float*)(ws + XT_OFF);

        hipMemsetAsync(ws, 0, 0x140200, stream);          // one memset for all state
        transpose_x<<<1024, 256, 0, stream>>>(x, xT);     // one-time, ~32MB of traffic

        for (int pass = 0; pass < 3; ++pass) {
            float* S = S3 + (size_t)pass * (BB * UK);
            float* Z = Z3 + (size_t)pass * 32;
            fused_mfma<<<NBLK, 512, 0, stream>>>(W, xT, vb, bio, S, Z);
            float* vo = (pass == 2) ? out : vb;
            squash_k<<<BB, UK, 0, stream>>>(S, Z, vo);
        }
    } else {
        // Fallback: proven LDS-broadcast path.
        float* S   = (float*)(ws);                         // 64 KB
        float* Z   = (float*)(ws + 65536);                 // 128 B (padded)
        float* vb  = (float*)(ws + 65536 + 256);           // 64 KB
        float* bio = (float*)(ws + 65536 + 256 + 65536);   // 1 MB

        hipMemsetAsync(vb,  0, BB * UK * 4, stream);
        hipMemsetAsync(bio, 0, CC * UU * 4, stream);

        for (int pass = 0; pass < 3; ++pass) {
            hipMemsetAsync(S, 0, BB * UK * 4, stream);
            hipMemsetAsync(Z, 0, UU * 4, stream);
            fused_pass_lds<<<256, 512, 0, stream>>>(x, W, vb, bio, S, Z);
            float* vo = (pass == 2) ? out : vb;
            squash_k<<<BB, UK, 0, stream>>>(S, Z, vo);
        }
    }
}